// Round 12
// baseline (474.666 us; speedup 1.0000x reference)
//
#include <hip/hip_runtime.h>
#include <math.h>

#define BB 32
#define CC 3
#define HH 224
#define WW 224
#define HWS (HH*WW)            // 50176
#define NPIX (BB*HWS)          // 1,605,632
#define NTAPS (9*HWS)          // 451,584
#define EPS_IN 1e-5f
#define LNUM 10

// 2D tile: 8 rows x 32 cols, halo RAD=4. Taps fully precomputed:
//  twm [9][HW] float4 : bilinear weights, border- AND window-masked
//  tmo4 [HW] int4     : LDS byte offsets of taps k=0..7 (u16 pairs)
//  tmx  [HW] u32      : offset k=8 | bad-mask<<16
// Cold fixup recomputes bad taps exactly from `off` (bit-identical math).
#define TR 8
#define TC 32
#define RAD 4
#define WROWS (TR + 2*RAD)         // 16
#define WCOLS (TC + 2*RAD)         // 40
#define WCELLS (WROWS * WCOLS)     // 640
#define WBYTES (WCELLS * 16)       // 10240 B per window
#define NTILE ((HH/TR) * (WW/TC))  // 28*7 = 196
#define NPAIR (BB/2)               // 16 batch pairs
#define NBLK2 (NTILE * NPAIR)      // 3136 blocks

typedef float f3v __attribute__((ext_vector_type(3)));   // 12B LDS reads (b96)

// tanh(z) = 1 - 2/(exp(2z)+1); saturates exactly, no clamp. 5 VALU.
__device__ __forceinline__ float fast_tanh(float z) {
    float e = __expf(2.f * z);
    return fmaf(-2.f, __frcp_rn(e + 1.f), 1.f);
}

__global__ void zero_kernel(float* __restrict__ p, int n) {
    int i = blockIdx.x * 256 + threadIdx.x;
    if (i < n) p[i] = 0.f;
}

// ------- per-PIXEL tap precompute (one thread = one pixel, loops 9 taps) ----
__global__ __launch_bounds__(256) void taps_kernel(
    const float* __restrict__ off,        // [18,H,W] batch-0 offset plane
    float4* __restrict__ twm,             // [9,HW]
    int4* __restrict__ tmo4,              // [HW]
    unsigned int* __restrict__ tmx)       // [HW]
{
    int pix = blockIdx.x * 256 + threadIdx.x;    // grid exact: HWS
    int h = pix / WW, wc = pix - h * WW;
    int ty = h / TR, tx = wc / TC;
    int wly = ty * TR - RAD, wlx = tx * TC - RAD;

    unsigned bm = 0u;
    unsigned offs[9];
    #pragma unroll
    for (int k = 0; k < 9; ++k) {
        int ky = k / 3, kx = k - 3 * ky;
        float dy = off[(2 * k)     * HWS + pix];
        float dx = off[(2 * k + 1) * HWS + pix];
        float py = (float)(h  + ky - 1) + dy;
        float px = (float)(wc + kx - 1) + dx;
        float y0f = floorf(py), x0f = floorf(px);
        float fy = py - y0f, fx = px - x0f;
        int iy0 = (int)y0f, ix0 = (int)x0f;
        int iy1 = iy0 + 1,  ix1 = ix0 + 1;
        float vy0 = (iy0 >= 0 && iy0 < HH) ? 1.f : 0.f;
        float vy1 = (iy1 >= 0 && iy1 < HH) ? 1.f : 0.f;
        float vx0 = (ix0 >= 0 && ix0 < WW) ? 1.f : 0.f;
        float vx1 = (ix1 >= 0 && ix1 < WW) ? 1.f : 0.f;

        int cy = iy0 - wly, cx = ix0 - wlx;
        bool inw = ((unsigned)cy <= (unsigned)(WROWS - 2)) &&
                   ((unsigned)cx <= (unsigned)(WCOLS - 2));
        float m = inw ? 1.f : 0.f;
        if (!inw) bm |= 1u << k;

        float4 w;
        w.x = (1.f - fy) * (1.f - fx) * vy0 * vx0 * m;
        w.y = (1.f - fy) * fx         * vy0 * vx1 * m;
        w.z = fy         * (1.f - fx) * vy1 * vx0 * m;
        w.w = fy         * fx         * vy1 * vx1 * m;
        twm[k * HWS + pix] = w;

        int cell = min(max(cy, 0), WROWS - 2) * WCOLS + min(max(cx, 0), WCOLS - 2);
        offs[k] = (unsigned)(cell * 16);
    }
    int4 m4;
    m4.x = (int)(offs[0] | (offs[1] << 16));
    m4.y = (int)(offs[2] | (offs[3] << 16));
    m4.z = (int)(offs[4] | (offs[5] << 16));
    m4.w = (int)(offs[6] | (offs[7] << 16));
    tmo4[pix] = m4;
    tmx[pix]  = offs[8] | (bm << 16);
}

__global__ __launch_bounds__(256) void pack_kernel(
    const float* __restrict__ x, float4* __restrict__ xi)
{
    int g = blockIdx.x * 256 + threadIdx.x;
    int b = g / HWS, pix = g - b * HWS;
    const float* xb = x + (size_t)b * (CC * HWS) + pix;
    xi[g] = make_float4(xb[0], xb[HWS], xb[2 * HWS], 0.f);
}

// R12: 2 batches per block in ONE phase-set. Residual theory after R5/R9/R11
// all-neutral: per-block phase serialization (stage-latency -> barrier ->
// DS-hot -> reduce) leaves the DS pipe ~50% idle; taps are batch-invariant,
// so one block now stages TWO batch windows (6 staging loads issued
// together), one barrier, one hot loop where each twk[k] feeds both windows
// (8 independent LDS reads), one reduction for both stats. Per pixel:
// global loads 14 -> 8.5, barriers and phase transitions halved, DS-hot
// unchanged. Unlike R6's regression: no serial re-barrier loop.
template<int DO_NORM>
__global__ __launch_bounds__(256, 3) void conv_fused(
    const float4* __restrict__ xi,        // prev RAW activations [B*HWS]
    const float4* __restrict__ twm,       // [9,HW]
    const int4* __restrict__ tmo4,        // [HW]
    const unsigned int* __restrict__ tmx, // [HW]
    const float* __restrict__ off,        // exact cold fixup
    const float* __restrict__ wt,         // [3,3,9] -> SGPRs via s_load
    const float* __restrict__ stats_in,   // [B*3][2] prev layer
    const float* __restrict__ gamma,
    const float* __restrict__ beta,
    float4* __restrict__ yo,              // RAW conv out [B*HWS]
    float* __restrict__ stats_out)        // [B*3][2] this layer
{
    __shared__ float4 win[2 * WCELLS];    // 20.5 KB (two windows)
    __shared__ float  red[4][8][12];

    int t = threadIdx.x;

    int p = blockIdx.x;
    int logical = (p & 7) * (NBLK2 / 8) + (p >> 3);
    int pr   = logical & 15;             // batch pair
    int tile = logical >> 4;             // 0..195
    int b0   = pr * 2;
    int ty = tile / 7, tx = tile - ty * 7;
    int by0 = ty * TR, bx0 = tx * TC;
    int wly = by0 - RAD, wlx = bx0 - RAD;

    const float4* xb0 = xi + (size_t)b0 * HWS;
    const float4* xb1 = xb0 + HWS;

    int ry = t >> 5, rx = t & 31;
    int pix = (by0 + ry) * WW + (bx0 + rx);

    // ---- issue ALL independent global loads up front (17 in flight) ----
    int4 m4 = tmo4[pix];
    unsigned mx = tmx[pix];

    int c0 = t, c1 = t + 256, c2 = t + 512;
    bool sval2 = (c2 < WCELLS);
    int so0, so1, so2;
    {
        int wy = c0 / WCOLS, wx = c0 - wy * WCOLS;
        so0 = min(max(wly + wy, 0), HH - 1) * WW + min(max(wlx + wx, 0), WW - 1);
        wy = c1 / WCOLS; wx = c1 - wy * WCOLS;
        so1 = min(max(wly + wy, 0), HH - 1) * WW + min(max(wlx + wx, 0), WW - 1);
        wy = c2 / WCOLS; wx = c2 - wy * WCOLS;
        so2 = min(max(wly + wy, 0), HH - 1) * WW + min(max(wlx + wx, 0), WW - 1);
    }
    float4 a0 = xb0[so0], a1 = xb0[so1];
    float4 b0v = xb1[so0], b1v = xb1[so1];
    float4 a2 = make_float4(0.f,0.f,0.f,0.f), b2 = a2;
    if (sval2) { a2 = xb0[so2]; b2 = xb1[so2]; }

    float4 twk[9];
    #pragma unroll
    for (int k = 0; k < 9; ++k) twk[k] = twm[k * HWS + pix];

    int tbk[9];
    tbk[0] = ((unsigned)m4.x) & 0xffff; tbk[1] = ((unsigned)m4.x) >> 16;
    tbk[2] = ((unsigned)m4.y) & 0xffff; tbk[3] = ((unsigned)m4.y) >> 16;
    tbk[4] = ((unsigned)m4.z) & 0xffff; tbk[5] = ((unsigned)m4.z) >> 16;
    tbk[6] = ((unsigned)m4.w) & 0xffff; tbk[7] = ((unsigned)m4.w) >> 16;
    tbk[8] = mx & 0xffff;
    unsigned bad = mx >> 16;

    // ---- uniform norm params (both batches) ----
    float mA0=0.f,mA1=0.f,mA2=0.f, gA0=1.f,gA1=1.f,gA2=1.f, bA0=0.f,bA1=0.f,bA2=0.f;
    float mB0=0.f,mB1=0.f,mB2=0.f, gB0=1.f,gB1=1.f,gB2=1.f, bB0=0.f,bB1=0.f,bB2=0.f;
    if (DO_NORM) {
        const float* st = stats_in + b0 * 6;
        mA0 = st[0]*(1.f/HWS); mA1 = st[2]*(1.f/HWS); mA2 = st[4]*(1.f/HWS);
        float v0 = fmaxf(st[1]*(1.f/HWS)-mA0*mA0, 0.f);
        float v1 = fmaxf(st[3]*(1.f/HWS)-mA1*mA1, 0.f);
        float v2 = fmaxf(st[5]*(1.f/HWS)-mA2*mA2, 0.f);
        gA0 = gamma[0]*rsqrtf(v0+EPS_IN); bA0 = beta[0];
        gA1 = gamma[1]*rsqrtf(v1+EPS_IN); bA1 = beta[1];
        gA2 = gamma[2]*rsqrtf(v2+EPS_IN); bA2 = beta[2];
        st += 6;
        mB0 = st[0]*(1.f/HWS); mB1 = st[2]*(1.f/HWS); mB2 = st[4]*(1.f/HWS);
        v0 = fmaxf(st[1]*(1.f/HWS)-mB0*mB0, 0.f);
        v1 = fmaxf(st[3]*(1.f/HWS)-mB1*mB1, 0.f);
        v2 = fmaxf(st[5]*(1.f/HWS)-mB2*mB2, 0.f);
        gB0 = gamma[0]*rsqrtf(v0+EPS_IN); bB0 = beta[0];
        gB1 = gamma[1]*rsqrtf(v1+EPS_IN); bB1 = beta[1];
        gB2 = gamma[2]*rsqrtf(v2+EPS_IN); bB2 = beta[2];
    }

    // ---- write both windows (norm+tanh applied on the fly) ----
    if (DO_NORM) {
        a0.x = fast_tanh((a0.x-mA0)*gA0+bA0); a0.y = fast_tanh((a0.y-mA1)*gA1+bA1); a0.z = fast_tanh((a0.z-mA2)*gA2+bA2);
        a1.x = fast_tanh((a1.x-mA0)*gA0+bA0); a1.y = fast_tanh((a1.y-mA1)*gA1+bA1); a1.z = fast_tanh((a1.z-mA2)*gA2+bA2);
        b0v.x = fast_tanh((b0v.x-mB0)*gB0+bB0); b0v.y = fast_tanh((b0v.y-mB1)*gB1+bB1); b0v.z = fast_tanh((b0v.z-mB2)*gB2+bB2);
        b1v.x = fast_tanh((b1v.x-mB0)*gB0+bB0); b1v.y = fast_tanh((b1v.y-mB1)*gB1+bB1); b1v.z = fast_tanh((b1v.z-mB2)*gB2+bB2);
    }
    win[c0] = a0; win[c1] = a1;
    win[WCELLS + c0] = b0v; win[WCELLS + c1] = b1v;
    if (sval2) {
        if (DO_NORM) {
            a2.x = fast_tanh((a2.x-mA0)*gA0+bA0); a2.y = fast_tanh((a2.y-mA1)*gA1+bA1); a2.z = fast_tanh((a2.z-mA2)*gA2+bA2);
            b2.x = fast_tanh((b2.x-mB0)*gB0+bB0); b2.y = fast_tanh((b2.y-mB1)*gB1+bB1); b2.z = fast_tanh((b2.z-mB2)*gB2+bB2);
        }
        win[c2] = a2;
        win[WCELLS + c2] = b2;
    }
    __syncthreads();

    // ---- hot loop: each twk[k] feeds BOTH windows (8 independent reads) ----
    float acA0 = 0.f, acA1 = 0.f, acA2 = 0.f;
    float acB0 = 0.f, acB1 = 0.f, acB2 = 0.f;

    #pragma unroll
    for (int k = 0; k < 9; ++k) {
        float4 w = twk[k];
        const char* cpA = (const char*)win + tbk[k];
        const char* cpB = cpA + WBYTES;

        f3v vA = *(const f3v*)cpA;
        f3v vB = *(const f3v*)cpB;
        float sA0 = vA.x*w.x, sA1 = vA.y*w.x, sA2 = vA.z*w.x;
        float sB0 = vB.x*w.x, sB1 = vB.y*w.x, sB2 = vB.z*w.x;
        vA = *(const f3v*)(cpA + 16);
        vB = *(const f3v*)(cpB + 16);
        sA0 = fmaf(vA.x,w.y,sA0); sA1 = fmaf(vA.y,w.y,sA1); sA2 = fmaf(vA.z,w.y,sA2);
        sB0 = fmaf(vB.x,w.y,sB0); sB1 = fmaf(vB.y,w.y,sB1); sB2 = fmaf(vB.z,w.y,sB2);
        vA = *(const f3v*)(cpA + 16 * WCOLS);
        vB = *(const f3v*)(cpB + 16 * WCOLS);
        sA0 = fmaf(vA.x,w.z,sA0); sA1 = fmaf(vA.y,w.z,sA1); sA2 = fmaf(vA.z,w.z,sA2);
        sB0 = fmaf(vB.x,w.z,sB0); sB1 = fmaf(vB.y,w.z,sB1); sB2 = fmaf(vB.z,w.z,sB2);
        vA = *(const f3v*)(cpA + 16 * WCOLS + 16);
        vB = *(const f3v*)(cpB + 16 * WCOLS + 16);
        sA0 = fmaf(vA.x,w.w,sA0); sA1 = fmaf(vA.y,w.w,sA1); sA2 = fmaf(vA.z,w.w,sA2);
        sB0 = fmaf(vB.x,w.w,sB0); sB1 = fmaf(vB.y,w.w,sB1); sB2 = fmaf(vB.z,w.w,sB2);

        acA0 = fmaf(sA2, wt[18+k], fmaf(sA1, wt[ 9+k], fmaf(sA0, wt[    k], acA0)));
        acA1 = fmaf(sA2, wt[45+k], fmaf(sA1, wt[36+k], fmaf(sA0, wt[27+k], acA1)));
        acA2 = fmaf(sA2, wt[72+k], fmaf(sA1, wt[63+k], fmaf(sA0, wt[54+k], acA2)));
        acB0 = fmaf(sB2, wt[18+k], fmaf(sB1, wt[ 9+k], fmaf(sB0, wt[    k], acB0)));
        acB1 = fmaf(sB2, wt[45+k], fmaf(sB1, wt[36+k], fmaf(sB0, wt[27+k], acB1)));
        acB2 = fmaf(sB2, wt[72+k], fmaf(sB1, wt[63+k], fmaf(sB0, wt[54+k], acB2)));
    }

    // ---- COLD fixup: out-of-window taps (batch-invariant mask) ----
    if (__builtin_expect(bad != 0u, 0)) {
        int h = pix / WW, wc = pix - h * WW;
        unsigned bb = bad;
        while (bb) {
            int k = __ffs(bb) - 1; bb &= bb - 1;
            int ky = k / 3, kx = k - 3 * ky;
            float dy = off[(2 * k)     * HWS + pix];
            float dx = off[(2 * k + 1) * HWS + pix];
            float py = (float)(h  + ky - 1) + dy;
            float px = (float)(wc + kx - 1) + dx;
            float y0f = floorf(py), x0f = floorf(px);
            float fy = py - y0f, fx = px - x0f;
            int iy0 = (int)y0f, ix0 = (int)x0f;
            int iy1 = iy0 + 1,  ix1 = ix0 + 1;
            float vy0 = (iy0 >= 0 && iy0 < HH) ? 1.f : 0.f;
            float vy1 = (iy1 >= 0 && iy1 < HH) ? 1.f : 0.f;
            float vx0 = (ix0 >= 0 && ix0 < WW) ? 1.f : 0.f;
            float vx1 = (ix1 >= 0 && ix1 < WW) ? 1.f : 0.f;
            float w00 = (1.f - fy) * (1.f - fx) * vy0 * vx0;
            float w01 = (1.f - fy) * fx         * vy0 * vx1;
            float w10 = fy         * (1.f - fx) * vy1 * vx0;
            float w11 = fy         * fx         * vy1 * vx1;
            int cy0 = min(max(iy0, 0), HH - 1), cy1 = min(max(iy1, 0), HH - 1);
            int cx0 = min(max(ix0, 0), WW - 1), cx1 = min(max(ix1, 0), WW - 1);
            int o00 = cy0 * WW + cx0, o01 = cy0 * WW + cx1;
            int o10 = cy1 * WW + cx0, o11 = cy1 * WW + cx1;

            // batch A
            float s0, s1, s2;
            float4 v = xb0[o00];
            if (DO_NORM) { v.x=fast_tanh((v.x-mA0)*gA0+bA0); v.y=fast_tanh((v.y-mA1)*gA1+bA1); v.z=fast_tanh((v.z-mA2)*gA2+bA2); }
            s0 = v.x*w00; s1 = v.y*w00; s2 = v.z*w00;
            v = xb0[o01];
            if (DO_NORM) { v.x=fast_tanh((v.x-mA0)*gA0+bA0); v.y=fast_tanh((v.y-mA1)*gA1+bA1); v.z=fast_tanh((v.z-mA2)*gA2+bA2); }
            s0 = fmaf(v.x,w01,s0); s1 = fmaf(v.y,w01,s1); s2 = fmaf(v.z,w01,s2);
            v = xb0[o10];
            if (DO_NORM) { v.x=fast_tanh((v.x-mA0)*gA0+bA0); v.y=fast_tanh((v.y-mA1)*gA1+bA1); v.z=fast_tanh((v.z-mA2)*gA2+bA2); }
            s0 = fmaf(v.x,w10,s0); s1 = fmaf(v.y,w10,s1); s2 = fmaf(v.z,w10,s2);
            v = xb0[o11];
            if (DO_NORM) { v.x=fast_tanh((v.x-mA0)*gA0+bA0); v.y=fast_tanh((v.y-mA1)*gA1+bA1); v.z=fast_tanh((v.z-mA2)*gA2+bA2); }
            s0 = fmaf(v.x,w11,s0); s1 = fmaf(v.y,w11,s1); s2 = fmaf(v.z,w11,s2);
            acA0 = fmaf(s2, wt[18+k], fmaf(s1, wt[ 9+k], fmaf(s0, wt[    k], acA0)));
            acA1 = fmaf(s2, wt[45+k], fmaf(s1, wt[36+k], fmaf(s0, wt[27+k], acA1)));
            acA2 = fmaf(s2, wt[72+k], fmaf(s1, wt[63+k], fmaf(s0, wt[54+k], acA2)));

            // batch B
            v = xb1[o00];
            if (DO_NORM) { v.x=fast_tanh((v.x-mB0)*gB0+bB0); v.y=fast_tanh((v.y-mB1)*gB1+bB1); v.z=fast_tanh((v.z-mB2)*gB2+bB2); }
            s0 = v.x*w00; s1 = v.y*w00; s2 = v.z*w00;
            v = xb1[o01];
            if (DO_NORM) { v.x=fast_tanh((v.x-mB0)*gB0+bB0); v.y=fast_tanh((v.y-mB1)*gB1+bB1); v.z=fast_tanh((v.z-mB2)*gB2+bB2); }
            s0 = fmaf(v.x,w01,s0); s1 = fmaf(v.y,w01,s1); s2 = fmaf(v.z,w01,s2);
            v = xb1[o10];
            if (DO_NORM) { v.x=fast_tanh((v.x-mB0)*gB0+bB0); v.y=fast_tanh((v.y-mB1)*gB1+bB1); v.z=fast_tanh((v.z-mB2)*gB2+bB2); }
            s0 = fmaf(v.x,w10,s0); s1 = fmaf(v.y,w10,s1); s2 = fmaf(v.z,w10,s2);
            v = xb1[o11];
            if (DO_NORM) { v.x=fast_tanh((v.x-mB0)*gB0+bB0); v.y=fast_tanh((v.y-mB1)*gB1+bB1); v.z=fast_tanh((v.z-mB2)*gB2+bB2); }
            s0 = fmaf(v.x,w11,s0); s1 = fmaf(v.y,w11,s1); s2 = fmaf(v.z,w11,s2);
            acB0 = fmaf(s2, wt[18+k], fmaf(s1, wt[ 9+k], fmaf(s0, wt[    k], acB0)));
            acB1 = fmaf(s2, wt[45+k], fmaf(s1, wt[36+k], fmaf(s0, wt[27+k], acB1)));
            acB2 = fmaf(s2, wt[72+k], fmaf(s1, wt[63+k], fmaf(s0, wt[54+k], acB2)));
        }
    }

    yo[(size_t)b0 * HWS + pix]       = make_float4(acA0, acA1, acA2, 0.f);
    yo[(size_t)(b0 + 1) * HWS + pix] = make_float4(acB0, acB1, acB2, 0.f);

    // ---- per-(b,channel) sum/sumsq, both batches in one pass ----
    float r0 = acA0, q0 = acA0*acA0;
    float r1 = acA1, q1 = acA1*acA1;
    float r2 = acA2, q2 = acA2*acA2;
    float r3 = acB0, q3 = acB0*acB0;
    float r4 = acB1, q4 = acB1*acB1;
    float r5 = acB2, q5 = acB2*acB2;
    #pragma unroll
    for (int o = 32; o >= 8; o >>= 1) {
        r0 += __shfl_down(r0, o); q0 += __shfl_down(q0, o);
        r1 += __shfl_down(r1, o); q1 += __shfl_down(q1, o);
        r2 += __shfl_down(r2, o); q2 += __shfl_down(q2, o);
        r3 += __shfl_down(r3, o); q3 += __shfl_down(q3, o);
        r4 += __shfl_down(r4, o); q4 += __shfl_down(q4, o);
        r5 += __shfl_down(r5, o); q5 += __shfl_down(q5, o);
    }
    int wave = t >> 6, lane = t & 63;
    if (lane < 8) {
        red[wave][lane][0]  = r0; red[wave][lane][1]  = q0;
        red[wave][lane][2]  = r1; red[wave][lane][3]  = q1;
        red[wave][lane][4]  = r2; red[wave][lane][5]  = q2;
        red[wave][lane][6]  = r3; red[wave][lane][7]  = q3;
        red[wave][lane][8]  = r4; red[wave][lane][9]  = q4;
        red[wave][lane][10] = r5; red[wave][lane][11] = q5;
    }
    __syncthreads();
    if (t < 12) {
        float v = 0.f;
        #pragma unroll
        for (int w = 0; w < 4; ++w)
            #pragma unroll
            for (int s = 0; s < 8; ++s)
                v += red[w][s][t];
        int batch = t / 6, rem = t - batch * 6;
        int ch = rem >> 1, which = rem & 1;
        atomicAdd(&stats_out[((b0 + batch) * 3 + ch) * 2 + which], v);
    }
}

__global__ __launch_bounds__(256) void norm_final(
    const float4* __restrict__ y, float* __restrict__ outp,
    const float* __restrict__ stats,
    const float* __restrict__ gamma, const float* __restrict__ beta)
{
    int q = blockIdx.x;
    int logical = (q & 7) * ((NPIX/256) / 8) + (q >> 3);
    int b     = logical & 31;
    int chunk = logical >> 5;
    int pix   = chunk * 256 + threadIdx.x;

    float4 v = y[b * HWS + pix];
    float vin[3] = {v.x, v.y, v.z};
    float r[3];
    #pragma unroll
    for (int c = 0; c < 3; ++c) {
        float s  = stats[(b * 3 + c) * 2 + 0];
        float qq = stats[(b * 3 + c) * 2 + 1];
        float mean = s * (1.f / HWS);
        float var  = fmaxf(qq * (1.f / HWS) - mean * mean, 0.f);
        float gsc  = gamma[c] * rsqrtf(var + EPS_IN);
        r[c] = fast_tanh((vin[c] - mean) * gsc + beta[c]);
    }
    float* ob = outp + (size_t)b * (CC * HWS) + pix;
    ob[0]       = r[0];
    ob[HWS]     = r[1];
    ob[2 * HWS] = r[2];
}

extern "C" void kernel_launch(void* const* d_in, const int* in_sizes, int n_in,
                              void* d_out, int out_size, void* d_ws, size_t ws_size,
                              hipStream_t stream) {
    const float* x     = (const float*)d_in[0];
    const float* wt    = (const float*)d_in[1];
    const float* off   = (const float*)d_in[2];
    const float* gamma = (const float*)d_in[3];
    const float* beta  = (const float*)d_in[4];

    float* out  = (float*)d_out;
    float*        bufA = (float*)d_ws;                              // 25.7 MB
    float*        bufB = bufA + (size_t)NPIX * 4;                   // 25.7 MB
    float4*       twm  = (float4*)(bufB + (size_t)NPIX * 4);        // 7.2 MB
    int4*         tmo4 = (int4*)((char*)twm + (size_t)NTAPS * 16);  // 0.8 MB
    unsigned int* tmx  = (unsigned int*)((char*)tmo4 + (size_t)HWS * 16); // 0.2 MB
    float*        stats = (float*)((char*)tmx + (size_t)HWS * 4);   // 7.7 KB
    // ws total ~= 60 MB

    zero_kernel<<<(LNUM * 192 + 255) / 256, 256, 0, stream>>>(stats, LNUM * 192);
    taps_kernel<<<HWS / 256, 256, 0, stream>>>(off, twm, tmo4, tmx);
    pack_kernel<<<NPIX / 256, 256, 0, stream>>>(x, (float4*)bufB);

    const float4* cur = (const float4*)bufB;
    const float* st_prev = nullptr;
    for (int it = 0; it < LNUM; ++it) {
        float4* dst = (float4*)((it & 1) ? bufB : bufA);
        float* st = stats + it * 192;
        if (it == 0)
            conv_fused<0><<<NBLK2, 256, 0, stream>>>(cur, twm, tmo4, tmx, off, wt, nullptr,
                                                     gamma, beta, dst, st);
        else
            conv_fused<1><<<NBLK2, 256, 0, stream>>>(cur, twm, tmo4, tmx, off, wt, st_prev,
                                                     gamma, beta, dst, st);
        cur = dst;
        st_prev = st;
    }
    norm_final<<<NPIX / 256, 256, 0, stream>>>(cur, out, st_prev, gamma, beta);
}

// Round 13
// 458.336 us; speedup vs baseline: 1.0356x; 1.0356x over previous
//
#include <hip/hip_runtime.h>
#include <math.h>

#define BB 32
#define CC 3
#define HH 224
#define WW 224
#define HWS (HH*WW)            // 50176
#define NPIX (BB*HWS)          // 1,605,632
#define NTAPS (9*HWS)          // 451,584
#define EPS_IN 1e-5f
#define LNUM 10

// 2D tile: 8 rows x 32 cols, halo RAD=4. Taps fully precomputed:
//  twm [9][HW] float4 : bilinear weights, border- AND window-masked
//  tmo4 [HW] int4     : LDS byte offsets of taps k=0..7 (u16 pairs)
//  tmx  [HW] u32      : offset k=8 | bad-mask<<16
// Cold fixup recomputes bad taps exactly from `off` (bit-identical math).
#define TR 8
#define TC 32
#define RAD 4
#define WROWS (TR + 2*RAD)         // 16
#define WCOLS (TC + 2*RAD)         // 40
#define WCELLS (WROWS * WCOLS)     // 640
#define NTILE ((HH/TR) * (WW/TC))  // 28*7 = 196
#define NBLK (NTILE * BB)          // 6272

typedef float f3v __attribute__((ext_vector_type(3)));   // 12B LDS reads (b96)

// tanh(z) = 1 - 2/(exp(2z)+1); saturates exactly (exp->inf => 1, ->0 => -1),
// no clamp needed. 5 VALU.
__device__ __forceinline__ float fast_tanh(float z) {
    float e = __expf(2.f * z);
    return fmaf(-2.f, __frcp_rn(e + 1.f), 1.f);
}

__global__ void zero_kernel(float* __restrict__ p, int n) {
    int i = blockIdx.x * 256 + threadIdx.x;
    if (i < n) p[i] = 0.f;
}

// ------- per-PIXEL tap precompute (one thread = one pixel, loops 9 taps) ----
__global__ __launch_bounds__(256) void taps_kernel(
    const float* __restrict__ off,        // [18,H,W] batch-0 offset plane
    float4* __restrict__ twm,             // [9,HW]
    int4* __restrict__ tmo4,              // [HW]
    unsigned int* __restrict__ tmx)       // [HW]
{
    int pix = blockIdx.x * 256 + threadIdx.x;    // grid exact: HWS
    int h = pix / WW, wc = pix - h * WW;
    int ty = h / TR, tx = wc / TC;
    int wly = ty * TR - RAD, wlx = tx * TC - RAD;

    unsigned bm = 0u;
    unsigned offs[9];
    #pragma unroll
    for (int k = 0; k < 9; ++k) {
        int ky = k / 3, kx = k - 3 * ky;
        float dy = off[(2 * k)     * HWS + pix];
        float dx = off[(2 * k + 1) * HWS + pix];
        float py = (float)(h  + ky - 1) + dy;
        float px = (float)(wc + kx - 1) + dx;
        float y0f = floorf(py), x0f = floorf(px);
        float fy = py - y0f, fx = px - x0f;
        int iy0 = (int)y0f, ix0 = (int)x0f;
        int iy1 = iy0 + 1,  ix1 = ix0 + 1;
        float vy0 = (iy0 >= 0 && iy0 < HH) ? 1.f : 0.f;
        float vy1 = (iy1 >= 0 && iy1 < HH) ? 1.f : 0.f;
        float vx0 = (ix0 >= 0 && ix0 < WW) ? 1.f : 0.f;
        float vx1 = (ix1 >= 0 && ix1 < WW) ? 1.f : 0.f;

        int cy = iy0 - wly, cx = ix0 - wlx;
        bool inw = ((unsigned)cy <= (unsigned)(WROWS - 2)) &&
                   ((unsigned)cx <= (unsigned)(WCOLS - 2));
        float m = inw ? 1.f : 0.f;
        if (!inw) bm |= 1u << k;

        float4 w;
        w.x = (1.f - fy) * (1.f - fx) * vy0 * vx0 * m;
        w.y = (1.f - fy) * fx         * vy0 * vx1 * m;
        w.z = fy         * (1.f - fx) * vy1 * vx0 * m;
        w.w = fy         * fx         * vy1 * vx1 * m;
        twm[k * HWS + pix] = w;

        int cell = min(max(cy, 0), WROWS - 2) * WCOLS + min(max(cx, 0), WCOLS - 2);
        offs[k] = (unsigned)(cell * 16);
    }
    int4 m4;
    m4.x = (int)(offs[0] | (offs[1] << 16));
    m4.y = (int)(offs[2] | (offs[3] << 16));
    m4.z = (int)(offs[4] | (offs[5] << 16));
    m4.w = (int)(offs[6] | (offs[7] << 16));
    tmo4[pix] = m4;
    tmx[pix]  = offs[8] | (bm << 16);
}

__global__ __launch_bounds__(256) void pack_kernel(
    const float* __restrict__ x, float4* __restrict__ xi)
{
    int g = blockIdx.x * 256 + threadIdx.x;
    int b = g / HWS, pix = g - b * HWS;
    const float* xb = x + (size_t)b * (CC * HWS) + pix;
    xi[g] = make_float4(xb[0], xb[HWS], xb[2 * HWS], 0.f);
}

// R13 = exact revert to R11 (best: 463.0 us). DS-pipe-trimmed flat kernel:
//  (1) corner reads as <3 x float> on the 16B-stride window -> ds_read_b96
//  (2) tap metadata packed pixel-major: int4+u32 (2 coalesced loads vs 10)
//  (3) exp-form tanh: 5 VALU, exact saturation, no clamp
//  Config: (256,4) + hoisted twk[9]. R12's 2-batch phase-amortized variant
//  regressed (475) -> phase-serialization theory falsified; ledger complete.
template<int DO_NORM>
__global__ __launch_bounds__(256, 4) void conv_fused(
    const float4* __restrict__ xi,        // prev RAW activations [B*HWS]
    const float4* __restrict__ twm,       // [9,HW]
    const int4* __restrict__ tmo4,        // [HW]
    const unsigned int* __restrict__ tmx, // [HW]
    const float* __restrict__ off,        // exact cold fixup
    const float* __restrict__ wt,         // [3,3,9] -> SGPRs via s_load
    const float* __restrict__ stats_in,   // [B*3][2] prev layer
    const float* __restrict__ gamma,
    const float* __restrict__ beta,
    float4* __restrict__ yo,              // RAW conv out [B*HWS]
    float* __restrict__ stats_out)        // [B*3][2] this layer
{
    __shared__ float4 win[WCELLS];
    __shared__ float  red[4][8][6];

    int t = threadIdx.x;

    int p = blockIdx.x;
    int logical = (p & 7) * (NBLK / 8) + (p >> 3);
    int b    = logical & 31;
    int tile = logical >> 5;             // 0..195
    int ty = tile / 7, tx = tile - ty * 7;
    int by0 = ty * TR, bx0 = tx * TC;
    int wly = by0 - RAD, wlx = bx0 - RAD;

    const float4* xb = xi + (size_t)b * HWS;

    int ry = t >> 5, rx = t & 31;
    int pix = (by0 + ry) * WW + (bx0 + rx);

    // packed tap metadata: 2 loads -> 9 offsets + bad mask
    int4 m4 = tmo4[pix];
    unsigned mx = tmx[pix];
    int tbk[9];
    tbk[0] = ((unsigned)m4.x) & 0xffff; tbk[1] = ((unsigned)m4.x) >> 16;
    tbk[2] = ((unsigned)m4.y) & 0xffff; tbk[3] = ((unsigned)m4.y) >> 16;
    tbk[4] = ((unsigned)m4.z) & 0xffff; tbk[5] = ((unsigned)m4.z) >> 16;
    tbk[6] = ((unsigned)m4.w) & 0xffff; tbk[7] = ((unsigned)m4.w) >> 16;
    tbk[8] = mx & 0xffff;
    unsigned bad = mx >> 16;

    // hoist tap weights (36 VGPR) — R8 best config
    float4 twk[9];
    #pragma unroll
    for (int k = 0; k < 9; ++k) twk[k] = twm[k * HWS + pix];

    // uniform per-(b,c) norm params of the PREVIOUS layer
    float mean0=0.f, mean1=0.f, mean2=0.f;
    float g0=1.f, g1=1.f, g2=1.f, bt0=0.f, bt1=0.f, bt2=0.f;
    if (DO_NORM) {
        const float* st = stats_in + b * 6;
        mean0 = st[0] * (1.f/HWS); mean1 = st[2] * (1.f/HWS); mean2 = st[4] * (1.f/HWS);
        float v0 = fmaxf(st[1]*(1.f/HWS) - mean0*mean0, 0.f);
        float v1 = fmaxf(st[3]*(1.f/HWS) - mean1*mean1, 0.f);
        float v2 = fmaxf(st[5]*(1.f/HWS) - mean2*mean2, 0.f);
        g0 = gamma[0] * rsqrtf(v0 + EPS_IN); bt0 = beta[0];
        g1 = gamma[1] * rsqrtf(v1 + EPS_IN); bt1 = beta[1];
        g2 = gamma[2] * rsqrtf(v2 + EPS_IN); bt2 = beta[2];
    }

    // ---- stage window (norm+tanh of prev layer applied on the fly) ----
    #pragma unroll
    for (int i = 0; i < 3; ++i) {
        int cell = t + i * 256;
        if (cell < WCELLS) {
            int wy = cell / WCOLS, wx = cell - wy * WCOLS;
            int gy = min(max(wly + wy, 0), HH - 1);   // clamp: value only used
            int gx = min(max(wlx + wx, 0), WW - 1);   // when weight != 0
            float4 v = xb[gy * WW + gx];
            if (DO_NORM) {
                v.x = fast_tanh((v.x - mean0) * g0 + bt0);
                v.y = fast_tanh((v.y - mean1) * g1 + bt1);
                v.z = fast_tanh((v.z - mean2) * g2 + bt2);
            }
            win[cell] = v;
        }
    }
    __syncthreads();

    float acc0 = 0.f, acc1 = 0.f, acc2 = 0.f;

    #pragma unroll
    for (int k = 0; k < 9; ++k) {
        float4 w = twk[k];
        const char* cp = (const char*)win + tbk[k];
        f3v v = *(const f3v*)cp;                            // ds_read_b96
        float s0 = v.x * w.x, s1 = v.y * w.x, s2 = v.z * w.x;
        v = *(const f3v*)(cp + 16);
        s0 = fmaf(v.x, w.y, s0); s1 = fmaf(v.y, w.y, s1); s2 = fmaf(v.z, w.y, s2);
        v = *(const f3v*)(cp + 16 * WCOLS);
        s0 = fmaf(v.x, w.z, s0); s1 = fmaf(v.y, w.z, s1); s2 = fmaf(v.z, w.z, s2);
        v = *(const f3v*)(cp + 16 * WCOLS + 16);
        s0 = fmaf(v.x, w.w, s0); s1 = fmaf(v.y, w.w, s1); s2 = fmaf(v.z, w.w, s2);

        // wt[] with constant indices: uniform address -> s_load -> SGPR operand
        acc0 = fmaf(s2, wt[18 + k], fmaf(s1, wt[ 9 + k], fmaf(s0, wt[     k], acc0)));
        acc1 = fmaf(s2, wt[45 + k], fmaf(s1, wt[36 + k], fmaf(s0, wt[27 + k], acc1)));
        acc2 = fmaf(s2, wt[72 + k], fmaf(s1, wt[63 + k], fmaf(s0, wt[54 + k], acc2)));
    }

    // ---- COLD fixup: out-of-window taps; recompute exactly from `off` ----
    if (__builtin_expect(bad != 0u, 0)) {
        int h = pix / WW, wc = pix - h * WW;
        unsigned bb = bad;
        while (bb) {
            int k = __ffs(bb) - 1; bb &= bb - 1;
            int ky = k / 3, kx = k - 3 * ky;
            float dy = off[(2 * k)     * HWS + pix];
            float dx = off[(2 * k + 1) * HWS + pix];
            float py = (float)(h  + ky - 1) + dy;
            float px = (float)(wc + kx - 1) + dx;
            float y0f = floorf(py), x0f = floorf(px);
            float fy = py - y0f, fx = px - x0f;
            int iy0 = (int)y0f, ix0 = (int)x0f;
            int iy1 = iy0 + 1,  ix1 = ix0 + 1;
            float vy0 = (iy0 >= 0 && iy0 < HH) ? 1.f : 0.f;
            float vy1 = (iy1 >= 0 && iy1 < HH) ? 1.f : 0.f;
            float vx0 = (ix0 >= 0 && ix0 < WW) ? 1.f : 0.f;
            float vx1 = (ix1 >= 0 && ix1 < WW) ? 1.f : 0.f;
            float w00 = (1.f - fy) * (1.f - fx) * vy0 * vx0;
            float w01 = (1.f - fy) * fx         * vy0 * vx1;
            float w10 = fy         * (1.f - fx) * vy1 * vx0;
            float w11 = fy         * fx         * vy1 * vx1;
            int cy0 = min(max(iy0, 0), HH - 1), cy1 = min(max(iy1, 0), HH - 1);
            int cx0 = min(max(ix0, 0), WW - 1), cx1 = min(max(ix1, 0), WW - 1);
            float s0, s1, s2;
            float4 v = xb[cy0 * WW + cx0];
            if (DO_NORM) { v.x = fast_tanh((v.x-mean0)*g0+bt0); v.y = fast_tanh((v.y-mean1)*g1+bt1); v.z = fast_tanh((v.z-mean2)*g2+bt2); }
            s0 = v.x * w00; s1 = v.y * w00; s2 = v.z * w00;
            v = xb[cy0 * WW + cx1];
            if (DO_NORM) { v.x = fast_tanh((v.x-mean0)*g0+bt0); v.y = fast_tanh((v.y-mean1)*g1+bt1); v.z = fast_tanh((v.z-mean2)*g2+bt2); }
            s0 = fmaf(v.x, w01, s0); s1 = fmaf(v.y, w01, s1); s2 = fmaf(v.z, w01, s2);
            v = xb[cy1 * WW + cx0];
            if (DO_NORM) { v.x = fast_tanh((v.x-mean0)*g0+bt0); v.y = fast_tanh((v.y-mean1)*g1+bt1); v.z = fast_tanh((v.z-mean2)*g2+bt2); }
            s0 = fmaf(v.x, w10, s0); s1 = fmaf(v.y, w10, s1); s2 = fmaf(v.z, w10, s2);
            v = xb[cy1 * WW + cx1];
            if (DO_NORM) { v.x = fast_tanh((v.x-mean0)*g0+bt0); v.y = fast_tanh((v.y-mean1)*g1+bt1); v.z = fast_tanh((v.z-mean2)*g2+bt2); }
            s0 = fmaf(v.x, w11, s0); s1 = fmaf(v.y, w11, s1); s2 = fmaf(v.z, w11, s2);
            acc0 = fmaf(s2, wt[18 + k], fmaf(s1, wt[ 9 + k], fmaf(s0, wt[     k], acc0)));
            acc1 = fmaf(s2, wt[45 + k], fmaf(s1, wt[36 + k], fmaf(s0, wt[27 + k], acc1)));
            acc2 = fmaf(s2, wt[72 + k], fmaf(s1, wt[63 + k], fmaf(s0, wt[54 + k], acc2)));
        }
    }

    yo[(size_t)b * HWS + pix] = make_float4(acc0, acc1, acc2, 0.f);

    // ---- per-(b,channel) sum/sumsq: 3-level butterfly (stop at 8 lanes) ----
    float s0r = acc0, q0 = acc0 * acc0;
    float s1r = acc1, q1 = acc1 * acc1;
    float s2r = acc2, q2 = acc2 * acc2;
    #pragma unroll
    for (int o = 32; o >= 8; o >>= 1) {
        s0r += __shfl_down(s0r, o); q0 += __shfl_down(q0, o);
        s1r += __shfl_down(s1r, o); q1 += __shfl_down(q1, o);
        s2r += __shfl_down(s2r, o); q2 += __shfl_down(q2, o);
    }
    int wave = t >> 6, lane = t & 63;
    if (lane < 8) {
        red[wave][lane][0] = s0r; red[wave][lane][1] = q0;
        red[wave][lane][2] = s1r; red[wave][lane][3] = q1;
        red[wave][lane][4] = s2r; red[wave][lane][5] = q2;
    }
    __syncthreads();
    if (t < 6) {
        float v = 0.f;
        #pragma unroll
        for (int w = 0; w < 4; ++w)
            #pragma unroll
            for (int s = 0; s < 8; ++s)
                v += red[w][s][t];
        int ch = t >> 1, which = t & 1;
        atomicAdd(&stats_out[(b * 3 + ch) * 2 + which], v);
    }
}

__global__ __launch_bounds__(256) void norm_final(
    const float4* __restrict__ y, float* __restrict__ outp,
    const float* __restrict__ stats,
    const float* __restrict__ gamma, const float* __restrict__ beta)
{
    int q = blockIdx.x;
    int logical = (q & 7) * ((NPIX/256) / 8) + (q >> 3);
    int b     = logical & 31;
    int chunk = logical >> 5;
    int pix   = chunk * 256 + threadIdx.x;

    float4 v = y[b * HWS + pix];
    float vin[3] = {v.x, v.y, v.z};
    float r[3];
    #pragma unroll
    for (int c = 0; c < 3; ++c) {
        float s  = stats[(b * 3 + c) * 2 + 0];
        float qq = stats[(b * 3 + c) * 2 + 1];
        float mean = s * (1.f / HWS);
        float var  = fmaxf(qq * (1.f / HWS) - mean * mean, 0.f);
        float gsc  = gamma[c] * rsqrtf(var + EPS_IN);
        r[c] = fast_tanh((vin[c] - mean) * gsc + beta[c]);
    }
    float* ob = outp + (size_t)b * (CC * HWS) + pix;
    ob[0]       = r[0];
    ob[HWS]     = r[1];
    ob[2 * HWS] = r[2];
}

extern "C" void kernel_launch(void* const* d_in, const int* in_sizes, int n_in,
                              void* d_out, int out_size, void* d_ws, size_t ws_size,
                              hipStream_t stream) {
    const float* x     = (const float*)d_in[0];
    const float* wt    = (const float*)d_in[1];
    const float* off   = (const float*)d_in[2];
    const float* gamma = (const float*)d_in[3];
    const float* beta  = (const float*)d_in[4];

    float* out  = (float*)d_out;
    float*        bufA = (float*)d_ws;                              // 25.7 MB
    float*        bufB = bufA + (size_t)NPIX * 4;                   // 25.7 MB
    float4*       twm  = (float4*)(bufB + (size_t)NPIX * 4);        // 7.2 MB
    int4*         tmo4 = (int4*)((char*)twm + (size_t)NTAPS * 16);  // 0.8 MB
    unsigned int* tmx  = (unsigned int*)((char*)tmo4 + (size_t)HWS * 16); // 0.2 MB
    float*        stats = (float*)((char*)tmx + (size_t)HWS * 4);   // 7.7 KB
    // ws total ~= 60 MB

    zero_kernel<<<(LNUM * 192 + 255) / 256, 256, 0, stream>>>(stats, LNUM * 192);
    taps_kernel<<<HWS / 256, 256, 0, stream>>>(off, twm, tmo4, tmx);
    pack_kernel<<<NPIX / 256, 256, 0, stream>>>(x, (float4*)bufB);

    const float4* cur = (const float4*)bufB;
    const float* st_prev = nullptr;
    for (int it = 0; it < LNUM; ++it) {
        float4* dst = (float4*)((it & 1) ? bufB : bufA);
        float* st = stats + it * 192;
        if (it == 0)
            conv_fused<0><<<NBLK, 256, 0, stream>>>(cur, twm, tmo4, tmx, off, wt, nullptr,
                                                    gamma, beta, dst, st);
        else
            conv_fused<1><<<NBLK, 256, 0, stream>>>(cur, twm, tmo4, tmx, off, wt, st_prev,
                                                    gamma, beta, dst, st);
        cur = dst;
        st_prev = st;
    }
    norm_final<<<NPIX / 256, 256, 0, stream>>>(cur, out, st_prev, gamma, beta);
}